// Round 1
// baseline (2083.390 us; speedup 1.0000x reference)
//
#include <hip/hip_runtime.h>
#include <hip/hip_bf16.h>

#define TSTEPS 2048
#define NB 64
#define DH 256

typedef __attribute__((ext_vector_type(8))) short short8;
typedef __attribute__((ext_vector_type(4))) float f32x4;

__device__ __forceinline__ unsigned short f2bf(float f) {
  union { float f; unsigned u; } v; v.f = f;
  unsigned u = v.u;
  u += 0x7FFFu + ((u >> 16) & 1u);   // round-to-nearest-even
  return (unsigned short)(u >> 16);
}

__device__ __forceinline__ float fast_tanh(float x) {
  // tanh(x) = 1 - 2/(e^{2x}+1); saturates correctly at +/-1 (inf/0 paths)
  float e = __builtin_amdgcn_exp2f(x * 2.885390081777927f);  // e^{2x}
  return 1.0f - 2.0f * __builtin_amdgcn_rcpf(e + 1.0f);
}

// ---- kernel 0: convert the three 256x256 f32 weight mats to bf16 ----
__global__ void cvt_w(const float* __restrict__ a, const float* __restrict__ b,
                      const float* __restrict__ c, unsigned short* __restrict__ dst) {
  int i = blockIdx.x * 256 + threadIdx.x;  // 0 .. 3*65536-1
  const float* s = (i < 65536) ? a : ((i < 131072) ? b : c);
  dst[i] = f2bf(s[i & 65535]);
}

// ---- kernels 1 & 3: C[M,256] = A[M,256] * W[256,256]^T  (W row-major [n][k], bf16)
// A is f32 (xproj) or bf16 (yproj). Each wave: 2 M-tiles of 16 rows, full N=256.
template <bool A_BF16>
__global__ __launch_bounds__(256) void gemm_nt(
    const void* __restrict__ Aptr, const unsigned short* __restrict__ Wbf,
    float* __restrict__ Cout) {
  const int w = threadIdx.x >> 6, l = threadIdx.x & 63;
  const int m16 = l & 15, kg = l >> 4;
  const long tile0 = ((long)blockIdx.x * 4 + w) * 2;

  short8 afr[2][8];
  for (int ti = 0; ti < 2; ++ti) {
    long row = (tile0 + ti) * 16 + m16;
    if (A_BF16) {
      const unsigned short* ar = (const unsigned short*)Aptr + row * 256 + kg * 8;
      for (int ks = 0; ks < 8; ++ks) afr[ti][ks] = *(const short8*)(ar + ks * 32);
    } else {
      const float* ar = (const float*)Aptr + row * 256 + kg * 8;
      for (int ks = 0; ks < 8; ++ks) {
        const float4* p = (const float4*)(ar + ks * 32);
        float4 f0 = p[0], f1 = p[1];
        short8 s;
        s[0] = (short)f2bf(f0.x); s[1] = (short)f2bf(f0.y);
        s[2] = (short)f2bf(f0.z); s[3] = (short)f2bf(f0.w);
        s[4] = (short)f2bf(f1.x); s[5] = (short)f2bf(f1.y);
        s[6] = (short)f2bf(f1.z); s[7] = (short)f2bf(f1.w);
        afr[ti][ks] = s;
      }
    }
  }
  for (int nt = 0; nt < 16; ++nt) {
    const int n = nt * 16 + m16;
    const unsigned short* wr = Wbf + n * 256 + kg * 8;
    f32x4 acc0 = {0.f, 0.f, 0.f, 0.f}, acc1 = {0.f, 0.f, 0.f, 0.f};
    for (int ks = 0; ks < 8; ++ks) {
      short8 b = *(const short8*)(wr + ks * 32);
      acc0 = __builtin_amdgcn_mfma_f32_16x16x32_bf16(afr[0][ks], b, acc0, 0, 0, 0);
      acc1 = __builtin_amdgcn_mfma_f32_16x16x32_bf16(afr[1][ks], b, acc1, 0, 0, 0);
    }
    for (int r = 0; r < 4; ++r) {
      Cout[(tile0 * 16 + kg * 4 + r) * 256 + n]       = acc0[r];
      Cout[((tile0 + 1) * 16 + kg * 4 + r) * 256 + n] = acc1[r];
    }
  }
}

// ---- kernel 2: the sequential scan. 16 blocks x 4 batch rows, 8 waves each.
// LDS h buffer stored directly in A-fragment order: hA[buf][ks][lane][8 bf16],
// element (m, c):  ks = c>>5, lane = m + 16*((c>>3)&3), e = c&7.
__global__ __launch_bounds__(512, 2) void rnn_scan(
    const float* __restrict__ xp, const unsigned short* __restrict__ Wbf,
    const float* __restrict__ h0, unsigned short* __restrict__ hs,
    float* __restrict__ hlast) {
  __shared__ unsigned short hA[2][8][64][8];
  const int tid = threadIdx.x, w = tid >> 6, l = tid & 63;
  const int b0 = blockIdx.x * 4;
  const int m16 = l & 15, kg = l >> 4;

  // W_hid B-fragments, resident in registers: wave owns cols [w*32, w*32+32)
  short8 bf[2][8];
  for (int nt = 0; nt < 2; ++nt) {
    int n = w * 32 + nt * 16 + m16;
    const unsigned short* wr = Wbf + n * 256 + kg * 8;
    for (int ks = 0; ks < 8; ++ks) bf[nt][ks] = *(const short8*)(wr + ks * 32);
  }

  for (int i = tid; i < 2 * 8 * 64 * 8; i += 512) ((unsigned short*)hA)[i] = 0;
  __syncthreads();
  for (int v = tid; v < 4 * 256; v += 512) {   // scatter h0 into frag order
    int m = v >> 8, c = v & 255;
    hA[0][c >> 5][m + 16 * ((c >> 3) & 3)][c & 7] = f2bf(h0[(b0 + m) * 256 + c]);
  }
  __syncthreads();

  const bool cact = (l < 16);                       // lanes holding real C rows (m=r)
  const unsigned short* abase = &hA[0][0][(m16 < 4) ? l : 0][0]; // inactive lanes: bcast slot 0
  const int col0 = w * 32 + l;                      // (cact) col for nt=0

  float xpr[8] = {0, 0, 0, 0, 0, 0, 0, 0};
  if (cact) {
    for (int nt = 0; nt < 2; ++nt)
      for (int r = 0; r < 4; ++r)
        xpr[nt * 4 + r] = xp[(long)(b0 + r) * 256 + col0 + nt * 16];
  }

  int cur = 0;
#pragma unroll 1
  for (int t = 0; t < TSTEPS; ++t) {
    f32x4 acc0, acc1;                               // C init = xp (no separate add)
    for (int r = 0; r < 4; ++r) { acc0[r] = xpr[r]; acc1[r] = xpr[4 + r]; }

    if (cact && t + 1 < TSTEPS) {                   // prefetch next step's xp
      const float* xq = xp + (long)(t + 1) * (NB * 256) + (long)b0 * 256 + col0;
      for (int nt = 0; nt < 2; ++nt)
        for (int r = 0; r < 4; ++r)
          xpr[nt * 4 + r] = xq[(long)r * 256 + nt * 16];
    }

    short8 a[8];
    const short8* ap = (const short8*)(abase + (long)cur * (8 * 64 * 8));
    for (int ks = 0; ks < 8; ++ks) a[ks] = ap[ks * 64];
    for (int ks = 0; ks < 8; ++ks) {
      acc0 = __builtin_amdgcn_mfma_f32_16x16x32_bf16(a[ks], bf[0][ks], acc0, 0, 0, 0);
      acc1 = __builtin_amdgcn_mfma_f32_16x16x32_bf16(a[ks], bf[1][ks], acc1, 0, 0, 0);
    }

    int nxt = cur ^ 1;
    if (cact) {
      unsigned short* hrow = hs + (long)t * (NB * 256) + (long)b0 * 256 + col0;
      for (int nt = 0; nt < 2; ++nt)
        for (int r = 0; r < 4; ++r) {
          float hvf = fast_tanh((nt == 0) ? acc0[r] : acc1[r]);
          unsigned short hb = f2bf(hvf);
          int c = col0 + nt * 16;
          hA[nxt][c >> 5][r + 16 * ((c >> 3) & 3)][c & 7] = hb;
          hrow[(long)r * 256 + nt * 16] = hb;
          if (t == TSTEPS - 1) hlast[(long)(b0 + r) * 256 + c] = hvf;
        }
    }
    __syncthreads();
    cur = nxt;
  }
}

extern "C" void kernel_launch(void* const* d_in, const int* in_sizes, int n_in,
                              void* d_out, int out_size, void* d_ws, size_t ws_size,
                              hipStream_t stream) {
  const float* x    = (const float*)d_in[0];
  const float* h0   = (const float*)d_in[1];
  const float* Win  = (const float*)d_in[2];
  const float* Whid = (const float*)d_in[3];
  const float* Wout = (const float*)d_in[4];
  float* ys    = (float*)d_out;
  float* hlast = ys + (long)TSTEPS * NB * 256;

  // d_ws layout: [bf16 W_in | bf16 W_hid | bf16 W_out | f32 xp (128MB) | bf16 hs (64MB)]
  unsigned short* wbf     = (unsigned short*)d_ws;
  unsigned short* wbf_in  = wbf;
  unsigned short* wbf_hid = wbf + 65536;
  unsigned short* wbf_out = wbf + 131072;
  float* xproj = (float*)((char*)d_ws + 393216);
  unsigned short* hsbuf =
      (unsigned short*)((char*)d_ws + 393216 + (size_t)TSTEPS * NB * 256 * 4);

  cvt_w<<<dim3(768), dim3(256), 0, stream>>>(Win, Whid, Wout, wbf);
  gemm_nt<false><<<dim3(1024), dim3(256), 0, stream>>>((const void*)x, wbf_in, xproj);
  rnn_scan<<<dim3(16), dim3(512), 0, stream>>>(xproj, wbf_hid, h0, hsbuf, hlast);
  gemm_nt<true><<<dim3(1024), dim3(256), 0, stream>>>((const void*)hsbuf, wbf_out, ys);
}

// Round 2
// 1986.009 us; speedup vs baseline: 1.0490x; 1.0490x over previous
//
#include <hip/hip_runtime.h>
#include <hip/hip_bf16.h>

#define TSTEPS 2048
#define NB 64
#define DH 256

typedef __attribute__((ext_vector_type(8))) short short8;
typedef __attribute__((ext_vector_type(4))) float f32x4;

__device__ __forceinline__ unsigned short f2bf(float f) {
  union { float f; unsigned u; } v; v.f = f;
  unsigned u = v.u;
  u += 0x7FFFu + ((u >> 16) & 1u);   // round-to-nearest-even
  return (unsigned short)(u >> 16);
}

__device__ __forceinline__ float fast_tanh(float x) {
  // tanh(x) = 1 - 2/(e^{2x}+1); saturates correctly at +/-1 (inf/0 paths)
  float e = __builtin_amdgcn_exp2f(x * 2.885390081777927f);  // e^{2x}
  return 1.0f - 2.0f * __builtin_amdgcn_rcpf(e + 1.0f);
}

// ---- kernel 0: convert the three 256x256 f32 weight mats to bf16 ----
__global__ void cvt_w(const float* __restrict__ a, const float* __restrict__ b,
                      const float* __restrict__ c, unsigned short* __restrict__ dst) {
  int i = blockIdx.x * 256 + threadIdx.x;  // 0 .. 3*65536-1
  const float* s = (i < 65536) ? a : ((i < 131072) ? b : c);
  dst[i] = f2bf(s[i & 65535]);
}

// ---- kernels 1 & 3: C[M,256] = A[M,256] * W[256,256]^T  (W row-major [n][k], bf16)
template <bool A_BF16>
__global__ __launch_bounds__(256) void gemm_nt(
    const void* __restrict__ Aptr, const unsigned short* __restrict__ Wbf,
    float* __restrict__ Cout) {
  const int w = threadIdx.x >> 6, l = threadIdx.x & 63;
  const int m16 = l & 15, kg = l >> 4;
  const long tile0 = ((long)blockIdx.x * 4 + w) * 2;

  short8 afr[2][8];
  for (int ti = 0; ti < 2; ++ti) {
    long row = (tile0 + ti) * 16 + m16;
    if (A_BF16) {
      const unsigned short* ar = (const unsigned short*)Aptr + row * 256 + kg * 8;
      for (int ks = 0; ks < 8; ++ks) afr[ti][ks] = *(const short8*)(ar + ks * 32);
    } else {
      const float* ar = (const float*)Aptr + row * 256 + kg * 8;
      for (int ks = 0; ks < 8; ++ks) {
        const float4* p = (const float4*)(ar + ks * 32);
        float4 f0 = p[0], f1 = p[1];
        short8 s;
        s[0] = (short)f2bf(f0.x); s[1] = (short)f2bf(f0.y);
        s[2] = (short)f2bf(f0.z); s[3] = (short)f2bf(f0.w);
        s[4] = (short)f2bf(f1.x); s[5] = (short)f2bf(f1.y);
        s[6] = (short)f2bf(f1.z); s[7] = (short)f2bf(f1.w);
        afr[ti][ks] = s;
      }
    }
  }
  for (int nt = 0; nt < 16; ++nt) {
    const int n = nt * 16 + m16;
    const unsigned short* wr = Wbf + n * 256 + kg * 8;
    f32x4 acc0 = {0.f, 0.f, 0.f, 0.f}, acc1 = {0.f, 0.f, 0.f, 0.f};
    for (int ks = 0; ks < 8; ++ks) {
      short8 b = *(const short8*)(wr + ks * 32);
      acc0 = __builtin_amdgcn_mfma_f32_16x16x32_bf16(afr[0][ks], b, acc0, 0, 0, 0);
      acc1 = __builtin_amdgcn_mfma_f32_16x16x32_bf16(afr[1][ks], b, acc1, 0, 0, 0);
    }
    for (int r = 0; r < 4; ++r) {
      Cout[(tile0 * 16 + kg * 4 + r) * 256 + n]       = acc0[r];
      Cout[((tile0 + 1) * 16 + kg * 4 + r) * 256 + n] = acc1[r];
    }
  }
}

// ---- kernel 2: the sequential scan. 16 blocks x 4 batch rows, 8 waves each.
// LDS h buffer in A-fragment order: hA[buf][ks][lane][8 bf16],
// element (m, c):  ks = c>>5, lane = m + 16*((c>>3)&3), e = c&7.
// Raw lgkm-only barrier: global xp loads / hs stores stay in flight across steps.
__global__ __launch_bounds__(512, 2) void rnn_scan(
    const float* __restrict__ xp, const unsigned short* __restrict__ Wbf,
    const float* __restrict__ h0, unsigned short* __restrict__ hs,
    float* __restrict__ hlast) {
  __shared__ unsigned short hA[2][8][64][8];
  const int tid = threadIdx.x, w = tid >> 6, l = tid & 63;
  const int b0 = blockIdx.x * 4;
  const int m16 = l & 15, kg = l >> 4;

  // W_hid B-fragments resident (unified VGPR/AGPR file): wave owns cols [w*32, w*32+32)
  short8 bf[2][8];
  for (int nt = 0; nt < 2; ++nt) {
    int n = w * 32 + nt * 16 + m16;
    const unsigned short* wr = Wbf + n * 256 + kg * 8;
    for (int ks = 0; ks < 8; ++ks) bf[nt][ks] = *(const short8*)(wr + ks * 32);
  }

  for (int i = tid; i < 2 * 8 * 64 * 8; i += 512) ((unsigned short*)hA)[i] = 0;
  __syncthreads();
  for (int v = tid; v < 4 * 256; v += 512) {   // scatter h0 into frag order
    int m = v >> 8, c = v & 255;
    hA[0][c >> 5][m + 16 * ((c >> 3) & 3)][c & 7] = f2bf(h0[(b0 + m) * 256 + c]);
  }
  __syncthreads();

  const bool cact = (l < 16);                       // lanes holding real C rows
  const unsigned short* abase = &hA[0][0][(m16 < 4) ? l : 0][0];
  const int col0 = w * 32 + l;                      // col for nt=0 (cact lanes)

  // 2-deep xp prefetch pipeline: xpA used at even t, xpB at odd t
  float xpA[8] = {0,0,0,0,0,0,0,0}, xpB[8] = {0,0,0,0,0,0,0,0};
  if (cact) {
    for (int nt = 0; nt < 2; ++nt)
      for (int r = 0; r < 4; ++r) {
        xpA[nt * 4 + r] = xp[(long)(b0 + r) * 256 + col0 + nt * 16];
        xpB[nt * 4 + r] = xp[(long)(NB * 256) + (long)(b0 + r) * 256 + col0 + nt * 16];
      }
  }

  int cur = 0;

#define RNN_STEP(T, XU)                                                              \
  {                                                                                  \
    short8 a[8];                                                                     \
    const short8* ap = (const short8*)(abase + (long)cur * (8 * 64 * 8));            \
    for (int ks = 0; ks < 8; ++ks) a[ks] = ap[ks * 64];                              \
    f32x4 acc0a, acc0b, acc1a, acc1b;                                                \
    for (int r = 0; r < 4; ++r) {                                                    \
      acc0a[r] = XU[r];  acc1a[r] = XU[4 + r];                                       \
      acc0b[r] = 0.f;    acc1b[r] = 0.f;                                             \
    }                                                                                \
    if (cact && (T) + 2 < TSTEPS) {  /* prefetch 2 steps ahead into same regs */     \
      const float* xq = xp + (long)((T) + 2) * (NB * 256) + (long)b0 * 256 + col0;   \
      for (int nt = 0; nt < 2; ++nt)                                                 \
        for (int r = 0; r < 4; ++r)                                                  \
          XU[nt * 4 + r] = xq[(long)r * 256 + nt * 16];                              \
    }                                                                                \
    for (int ks = 0; ks < 4; ++ks) {   /* 4 independent 4-deep chains */             \
      acc0a = __builtin_amdgcn_mfma_f32_16x16x32_bf16(a[ks], bf[0][ks], acc0a, 0, 0, 0); \
      acc1a = __builtin_amdgcn_mfma_f32_16x16x32_bf16(a[ks], bf[1][ks], acc1a, 0, 0, 0); \
    }                                                                                \
    for (int ks = 4; ks < 8; ++ks) {                                                 \
      acc0b = __builtin_amdgcn_mfma_f32_16x16x32_bf16(a[ks], bf[0][ks], acc0b, 0, 0, 0); \
      acc1b = __builtin_amdgcn_mfma_f32_16x16x32_bf16(a[ks], bf[1][ks], acc1b, 0, 0, 0); \
    }                                                                                \
    int nxt = cur ^ 1;                                                               \
    if (cact) {                                                                      \
      unsigned short* hrow = hs + (long)(T) * (NB * 256) + (long)b0 * 256 + col0;    \
      f32x4 s0 = acc0a + acc0b, s1 = acc1a + acc1b;                                  \
      for (int nt = 0; nt < 2; ++nt)                                                 \
        for (int r = 0; r < 4; ++r) {                                                \
          float hvf = fast_tanh((nt == 0) ? s0[r] : s1[r]);                          \
          unsigned short hb = f2bf(hvf);                                             \
          int c = col0 + nt * 16;                                                    \
          hA[nxt][c >> 5][r + 16 * ((c >> 3) & 3)][c & 7] = hb;                      \
          hrow[(long)r * 256 + nt * 16] = hb;                                        \
          if ((T) == TSTEPS - 1) hlast[(long)(b0 + r) * 256 + c] = hvf;              \
        }                                                                            \
    }                                                                                \
    asm volatile("s_waitcnt lgkmcnt(0)" ::: "memory");  /* LDS drain only */         \
    __builtin_amdgcn_s_barrier();                                                    \
    __builtin_amdgcn_sched_barrier(0);                                               \
    cur = nxt;                                                                       \
  }

#pragma unroll 1
  for (int t = 0; t < TSTEPS; t += 2) {
    RNN_STEP(t, xpA);
    RNN_STEP(t + 1, xpB);
  }
#undef RNN_STEP
}

extern "C" void kernel_launch(void* const* d_in, const int* in_sizes, int n_in,
                              void* d_out, int out_size, void* d_ws, size_t ws_size,
                              hipStream_t stream) {
  const float* x    = (const float*)d_in[0];
  const float* h0   = (const float*)d_in[1];
  const float* Win  = (const float*)d_in[2];
  const float* Whid = (const float*)d_in[3];
  const float* Wout = (const float*)d_in[4];
  float* ys    = (float*)d_out;
  float* hlast = ys + (long)TSTEPS * NB * 256;

  // d_ws layout: [bf16 W_in | bf16 W_hid | bf16 W_out | f32 xp (128MB) | bf16 hs (64MB)]
  unsigned short* wbf     = (unsigned short*)d_ws;
  unsigned short* wbf_in  = wbf;
  unsigned short* wbf_hid = wbf + 65536;
  unsigned short* wbf_out = wbf + 131072;
  float* xproj = (float*)((char*)d_ws + 393216);
  unsigned short* hsbuf =
      (unsigned short*)((char*)d_ws + 393216 + (size_t)TSTEPS * NB * 256 * 4);

  cvt_w<<<dim3(768), dim3(256), 0, stream>>>(Win, Whid, Wout, wbf);
  gemm_nt<false><<<dim3(1024), dim3(256), 0, stream>>>((const void*)x, wbf_in, xproj);
  rnn_scan<<<dim3(16), dim3(512), 0, stream>>>(xproj, wbf_hid, h0, hsbuf, hlast);
  gemm_nt<true><<<dim3(1024), dim3(256), 0, stream>>>((const void*)hsbuf, wbf_out, ys);
}

// Round 3
// 1037.742 us; speedup vs baseline: 2.0076x; 1.9138x over previous
//
#include <hip/hip_runtime.h>
#include <hip/hip_bf16.h>

#define TSTEPS 2048
#define NB 64
#define DH 256
#define NBDH (NB * DH)

typedef __attribute__((ext_vector_type(8))) short short8;
typedef __attribute__((ext_vector_type(4))) float f32x4;

__device__ __forceinline__ unsigned short f2bf(float f) {
  union { float f; unsigned u; } v; v.f = f;
  unsigned u = v.u;
  u += 0x7FFFu + ((u >> 16) & 1u);   // round-to-nearest-even
  return (unsigned short)(u >> 16);
}

__device__ __forceinline__ float fast_tanh(float x) {
  // tanh(x) = 1 - 2/(e^{2x}+1); saturates correctly at +/-1
  float e = __builtin_amdgcn_exp2f(x * 2.885390081777927f);  // e^{2x}
  return 1.0f - 2.0f * __builtin_amdgcn_rcpf(e + 1.0f);
}

// ---- kernel 0: convert the three 256x256 f32 weight mats to bf16 ----
__global__ void cvt_w(const float* __restrict__ a, const float* __restrict__ b,
                      const float* __restrict__ c, unsigned short* __restrict__ dst) {
  int i = blockIdx.x * 256 + threadIdx.x;  // 0 .. 3*65536-1
  const float* s = (i < 65536) ? a : ((i < 131072) ? b : c);
  dst[i] = f2bf(s[i & 65535]);
}

// ---- kernels 1 & 3: C[M,256] = A[M,256] * W[256,256]^T  (W row-major [n][k], bf16)
template <bool A_BF16>
__global__ __launch_bounds__(256) void gemm_nt(
    const void* __restrict__ Aptr, const unsigned short* __restrict__ Wbf,
    float* __restrict__ Cout) {
  const int w = threadIdx.x >> 6, l = threadIdx.x & 63;
  const int m16 = l & 15, kg = l >> 4;
  const long tile0 = ((long)blockIdx.x * 4 + w) * 2;

  short8 afr[2][8];
  for (int ti = 0; ti < 2; ++ti) {
    long row = (tile0 + ti) * 16 + m16;
    if (A_BF16) {
      const unsigned short* ar = (const unsigned short*)Aptr + row * 256 + kg * 8;
      for (int ks = 0; ks < 8; ++ks) afr[ti][ks] = *(const short8*)(ar + ks * 32);
    } else {
      const float* ar = (const float*)Aptr + row * 256 + kg * 8;
      for (int ks = 0; ks < 8; ++ks) {
        const float4* p = (const float4*)(ar + ks * 32);
        float4 f0 = p[0], f1 = p[1];
        short8 s;
        s[0] = (short)f2bf(f0.x); s[1] = (short)f2bf(f0.y);
        s[2] = (short)f2bf(f0.z); s[3] = (short)f2bf(f0.w);
        s[4] = (short)f2bf(f1.x); s[5] = (short)f2bf(f1.y);
        s[6] = (short)f2bf(f1.z); s[7] = (short)f2bf(f1.w);
        afr[ti][ks] = s;
      }
    }
  }
  for (int nt = 0; nt < 16; ++nt) {
    const int n = nt * 16 + m16;
    const unsigned short* wr = Wbf + n * 256 + kg * 8;
    f32x4 acc0 = {0.f, 0.f, 0.f, 0.f}, acc1 = {0.f, 0.f, 0.f, 0.f};
    for (int ks = 0; ks < 8; ++ks) {
      short8 b = *(const short8*)(wr + ks * 32);
      acc0 = __builtin_amdgcn_mfma_f32_16x16x32_bf16(afr[0][ks], b, acc0, 0, 0, 0);
      acc1 = __builtin_amdgcn_mfma_f32_16x16x32_bf16(afr[1][ks], b, acc1, 0, 0, 0);
    }
    for (int r = 0; r < 4; ++r) {
      Cout[(tile0 * 16 + kg * 4 + r) * 256 + n]       = acc0[r];
      Cout[((tile0 + 1) * 16 + kg * 4 + r) * 256 + n] = acc1[r];
    }
  }
}

// ---- kernel 2: sequential scan. 64 blocks x 1 batch row, 8 waves x 32 cols.
// h stored in LDS LINEARLY by column: hA[buf][c], c = ks*32 + kg*8 + e — which
// IS A-fragment order for M=1 (active A lanes l = 16*kg read 16B at c = ks*32+kg*8).
// Reads: 4 distinct 16B chunks, conflict-free; other 60 lanes broadcast-share.
// Writes: 16 consecutive b16 per (wave,nt) = 2-way pairs = free.
__global__ __launch_bounds__(512, 2) void rnn_scan(
    const float* __restrict__ xp, const unsigned short* __restrict__ Wbf,
    const float* __restrict__ h0, unsigned short* __restrict__ hs) {
  __shared__ unsigned short hA[2][256];
  const int tid = threadIdx.x, w = tid >> 6, l = tid & 63;
  const int b = blockIdx.x;           // one batch row per block
  const int m16 = l & 15, kg = l >> 4;

  // W_hid B-fragments resident: wave owns cols [w*32, w*32+32), 2 tiles
  short8 bf0[8], bf1[8];
  {
    const unsigned short* wr0 = Wbf + (w * 32 + m16) * 256 + kg * 8;
    const unsigned short* wr1 = Wbf + (w * 32 + 16 + m16) * 256 + kg * 8;
    for (int ks = 0; ks < 8; ++ks) {
      bf0[ks] = *(const short8*)(wr0 + ks * 32);
      bf1[ks] = *(const short8*)(wr1 + ks * 32);
    }
  }

  if (tid < 256) hA[0][tid] = f2bf(h0[b * 256 + tid]);
  __syncthreads();

  const int col0 = w * 32 + m16;
  const unsigned short* rdp = &hA[0][0] + kg * 8;     // + CUR*256 + ks*32 (imm)
  const float* xpb = xp + (long)b * 256 + col0;       // + t*NBDH
  unsigned short* hsb = hs + (long)b * 256 + col0;    // + t*NBDH

  // 4-deep xp prefetch rotation (prefetch distance 4 ≈ full HBM latency cover)
  float xv0[2], xv1[2], xv2[2], xv3[2];
  xv0[0] = xpb[0];               xv0[1] = xpb[16];
  xv1[0] = xpb[1L * NBDH];       xv1[1] = xpb[1L * NBDH + 16];
  xv2[0] = xpb[2L * NBDH];       xv2[1] = xpb[2L * NBDH + 16];
  xv3[0] = xpb[3L * NBDH];       xv3[1] = xpb[3L * NBDH + 16];

#define MFMA_BF16 __builtin_amdgcn_mfma_f32_16x16x32_bf16
#define RNN_STEP(T, CUR, XV, PF)                                              \
  {                                                                           \
    const short8* ap = (const short8*)(rdp + (CUR) * 256);                    \
    short8 a0 = ap[0], a1 = ap[4], a2 = ap[8],  a3 = ap[12];                  \
    short8 a4 = ap[16], a5 = ap[20], a6 = ap[24], a7 = ap[28];                \
    f32x4 c0a = {XV[0], 0.f, 0.f, 0.f};                                       \
    f32x4 c1a = {XV[1], 0.f, 0.f, 0.f};                                       \
    f32x4 c0b = {0.f, 0.f, 0.f, 0.f};                                         \
    f32x4 c1b = {0.f, 0.f, 0.f, 0.f};                                         \
    if (PF) {                                                                 \
      const float* q = xpb + (long)((T) + 4) * NBDH;                          \
      XV[0] = q[0]; XV[1] = q[16];                                            \
    }                                                                         \
    c0a = MFMA_BF16(a0, bf0[0], c0a, 0, 0, 0);                                \
    c1a = MFMA_BF16(a0, bf1[0], c1a, 0, 0, 0);                                \
    c0a = MFMA_BF16(a1, bf0[1], c0a, 0, 0, 0);                                \
    c1a = MFMA_BF16(a1, bf1[1], c1a, 0, 0, 0);                                \
    c0a = MFMA_BF16(a2, bf0[2], c0a, 0, 0, 0);                                \
    c1a = MFMA_BF16(a2, bf1[2], c1a, 0, 0, 0);                                \
    c0a = MFMA_BF16(a3, bf0[3], c0a, 0, 0, 0);                                \
    c1a = MFMA_BF16(a3, bf1[3], c1a, 0, 0, 0);                                \
    c0b = MFMA_BF16(a4, bf0[4], c0b, 0, 0, 0);                                \
    c1b = MFMA_BF16(a4, bf1[4], c1b, 0, 0, 0);                                \
    c0b = MFMA_BF16(a5, bf0[5], c0b, 0, 0, 0);                                \
    c1b = MFMA_BF16(a5, bf1[5], c1b, 0, 0, 0);                                \
    c0b = MFMA_BF16(a6, bf0[6], c0b, 0, 0, 0);                                \
    c1b = MFMA_BF16(a6, bf1[6], c1b, 0, 0, 0);                                \
    c0b = MFMA_BF16(a7, bf0[7], c0b, 0, 0, 0);                                \
    c1b = MFMA_BF16(a7, bf1[7], c1b, 0, 0, 0);                                \
    float t0 = fast_tanh(c0a[0] + c0b[0]);                                    \
    float t1 = fast_tanh(c1a[0] + c1b[0]);                                    \
    if (l < 16) {                                                             \
      unsigned short u0 = f2bf(t0), u1 = f2bf(t1);                            \
      hA[(CUR) ^ 1][w * 32 + l]      = u0;                                    \
      hA[(CUR) ^ 1][w * 32 + 16 + l] = u1;                                    \
      unsigned short* hr = hsb + (long)(T) * NBDH;                            \
      hr[0] = u0; hr[16] = u1;                                                \
    }                                                                         \
    asm volatile("s_waitcnt lgkmcnt(0)" ::: "memory");  /* LDS drain only */  \
    __builtin_amdgcn_s_barrier();                                             \
    __builtin_amdgcn_sched_barrier(0);                                        \
  }

#pragma unroll 1
  for (int t = 0; t < TSTEPS - 4; t += 4) {
    RNN_STEP(t, 0, xv0, true);
    RNN_STEP(t + 1, 1, xv1, true);
    RNN_STEP(t + 2, 0, xv2, true);
    RNN_STEP(t + 3, 1, xv3, true);
  }
  RNN_STEP(TSTEPS - 4, 0, xv0, false);
  RNN_STEP(TSTEPS - 3, 1, xv1, false);
  RNN_STEP(TSTEPS - 2, 0, xv2, false);
  RNN_STEP(TSTEPS - 1, 1, xv3, false);
#undef RNN_STEP
#undef MFMA_BF16
}

// ---- kernel 4: h_last = f32(hs[T-1])
__global__ void hlast_k(const unsigned short* __restrict__ hs, float* __restrict__ hlast) {
  int i = blockIdx.x * 1024 + threadIdx.x;          // 16 blocks x 1024 = 16384
  unsigned u = (unsigned)hs[(long)(TSTEPS - 1) * NBDH + i] << 16;
  union { unsigned u; float f; } v; v.u = u;
  hlast[i] = v.f;
}

extern "C" void kernel_launch(void* const* d_in, const int* in_sizes, int n_in,
                              void* d_out, int out_size, void* d_ws, size_t ws_size,
                              hipStream_t stream) {
  const float* x    = (const float*)d_in[0];
  const float* h0   = (const float*)d_in[1];
  const float* Win  = (const float*)d_in[2];
  const float* Whid = (const float*)d_in[3];
  const float* Wout = (const float*)d_in[4];
  float* ys    = (float*)d_out;
  float* hlast = ys + (long)TSTEPS * NB * 256;

  // d_ws layout: [bf16 W_in | bf16 W_hid | bf16 W_out | f32 xp (128MB) | bf16 hs (64MB)]
  unsigned short* wbf     = (unsigned short*)d_ws;
  unsigned short* wbf_in  = wbf;
  unsigned short* wbf_hid = wbf + 65536;
  unsigned short* wbf_out = wbf + 131072;
  float* xproj = (float*)((char*)d_ws + 393216);
  unsigned short* hsbuf =
      (unsigned short*)((char*)d_ws + 393216 + (size_t)TSTEPS * NB * 256 * 4);

  cvt_w<<<dim3(768), dim3(256), 0, stream>>>(Win, Whid, Wout, wbf);
  gemm_nt<false><<<dim3(1024), dim3(256), 0, stream>>>((const void*)x, wbf_in, xproj);
  rnn_scan<<<dim3(64), dim3(512), 0, stream>>>(xproj, wbf_hid, h0, hsbuf);
  gemm_nt<true><<<dim3(1024), dim3(256), 0, stream>>>((const void*)hsbuf, wbf_out, ys);
  hlast_k<<<dim3(16), dim3(1024), 0, stream>>>(hsbuf, hlast);
}